// Round 3
// baseline (273.658 us; speedup 1.0000x reference)
//
#include <hip/hip_runtime.h>
#include <hip/hip_bf16.h>
#include <stdint.h>

// WeightOnlyPerChannelQuantizedLinear: out[b,n] = (sum_k x[b,k]*w[n,k]) * scale[n]
// x: fp32 [16][8192], w: int8 values stored as int32 [28672][8192], scale: fp32 [28672]
// HBM-bound on the 940 MB int32 weight stream. bf16 MFMA 16x16x32 (int8->bf16 exact).
//
// R3 = R2 with the nontemporal loads done through a clang ext_vector type
// (HIP's int4 is a class; __builtin_nontemporal_load rejects it).
// R2 changes vs R1 (211.6 us, 4.44 TB/s):
//  - nt weight loads: read-once 940 MB stream must not evict the 256 KB afrag
//    table from L2 (448 MB of afrag re-reads ride on L2 hits).
//  - 64 B contiguous per lane / 256 B per weight row per iteration (2 MFMAs).

using f32x4 = __attribute__((ext_vector_type(4))) float;
using s16x8 = __attribute__((ext_vector_type(8))) short;
using i32x4 = __attribute__((ext_vector_type(4))) int;

static constexpr int K      = 8192;
static constexpr int N      = 28672;
static constexpr int KSTEP  = 32;           // K per MFMA
static constexpr int NSTEPS = K / KSTEP;    // 256 MFMA k-steps total
static constexpr int WAVES  = 4;            // waves per block, split-K
static constexpr int KW     = K / WAVES;    // 2048 k per wave
static constexpr int SW     = KW / KSTEP;   // 64 MFMA steps per wave
static constexpr int ITERS  = SW / 2;       // 32 iterations, 2 MFMAs each

// ---------------------------------------------------------------------------
// Pre-pass: fp32 activations [16][K] -> bf16 MFMA A-fragments (RNE).
// k-mapping (must match the weight-side loads): global MFMA step kk = i*2+sub,
//   lane l = (q<<4)|row holds A[row][ i*64 + q*16 + sub*8 + j ], j=0..7,
// packed as 4 dwords (even j low half). afrag[kk*64 + l] is one uint4, so the
// main kernel's per-step fragment load is 64 lanes x 16 B = 1 KB contiguous.
// ---------------------------------------------------------------------------
__global__ __launch_bounds__(256) void prep_a_kernel(const float* __restrict__ act,
                                                     uint4* __restrict__ afrag) {
  const int t   = blockIdx.x * 256 + threadIdx.x;  // 0 .. NSTEPS*64-1
  const int kk  = t >> 6;
  const int l   = t & 63;
  const int row = l & 15;
  const int q   = l >> 4;
  const int i   = kk >> 1;
  const int sub = kk & 1;
  const float* src = act + row * K + i * 64 + q * 16 + sub * 8;
  uint d[4];
#pragma unroll
  for (int p = 0; p < 4; ++p) {
    uint u0 = __builtin_bit_cast(uint, src[2 * p]);
    uint u1 = __builtin_bit_cast(uint, src[2 * p + 1]);
    u0 += 0x7fffu + ((u0 >> 16) & 1u);            // RNE f32 -> bf16
    u1 += 0x7fffu + ((u1 >> 16) & 1u);
    d[p] = (u0 >> 16) | (u1 & 0xffff0000u);       // even j low, odd j high
  }
  afrag[t] = make_uint4(d[0], d[1], d[2], d[3]);
}

// pack two f32-bit-patterns' bf16 truncations (exact for small ints)
__device__ __forceinline__ uint pack_bf16(int a, int b) {
  uint fa = __builtin_bit_cast(uint, (float)a);
  uint fb = __builtin_bit_cast(uint, (float)b);
  return (fa >> 16) | (fb & 0xffff0000u);
}

// ---------------------------------------------------------------------------
// Main kernel: one block = 16 output channels, 4 waves split K in quarters.
// Per wave per iteration: lane (r,q) loads 64 B contiguous int32 weights
// (row n0+r, words i*64 + q*16 .. +16) with nt; rows get 256 B bursts.
// Two MFMAs per iteration (sub-steps j=0..7 and j=8..15).
// Epilogue: LDS reduce over 4 waves, per-channel scale.
// ---------------------------------------------------------------------------
__global__ __launch_bounds__(256) void wq_linear_kernel(
    const int* __restrict__ wt,        // int32 [N][K]
    const uint4* __restrict__ afrag,   // [NSTEPS][64]
    const float* __restrict__ scaler,  // [N]
    float* __restrict__ out) {         // [16][N]
  __shared__ float red[WAVES][256];
  const int tid = threadIdx.x;
  const int l   = tid & 63;
  const int w   = tid >> 6;
  const int n0  = blockIdx.x << 4;
  const int r   = l & 15;           // output channel within tile (B column)
  const int q   = l >> 4;           // k-chunk selector

  const i32x4* wp = (const i32x4*)(wt + (size_t)(n0 + r) * K + w * KW + q * 16);
  const uint4* ap = afrag + (size_t)(w * SW) * 64 + l;

  f32x4 acc = {0.f, 0.f, 0.f, 0.f};

#pragma unroll 2
  for (int i = 0; i < ITERS; ++i) {
    const uint4 av0 = ap[0];
    const uint4 av1 = ap[64];
    const i32x4 w0 = __builtin_nontemporal_load(wp);      // words  0..3
    const i32x4 w1 = __builtin_nontemporal_load(wp + 1);  // words  4..7
    const i32x4 w2 = __builtin_nontemporal_load(wp + 2);  // words  8..11
    const i32x4 w3 = __builtin_nontemporal_load(wp + 3);  // words 12..15
    ap += 128;           // two steps ahead
    wp += 16;            // 64 int32 ahead

    const uint b00 = pack_bf16(w0.x, w0.y);
    const uint b01 = pack_bf16(w0.z, w0.w);
    const uint b02 = pack_bf16(w1.x, w1.y);
    const uint b03 = pack_bf16(w1.z, w1.w);
    const uint b10 = pack_bf16(w2.x, w2.y);
    const uint b11 = pack_bf16(w2.z, w2.w);
    const uint b12 = pack_bf16(w3.x, w3.y);
    const uint b13 = pack_bf16(w3.z, w3.w);

    s16x8 a0 = __builtin_bit_cast(s16x8, av0);
    s16x8 b0 = __builtin_bit_cast(s16x8, make_uint4(b00, b01, b02, b03));
    acc = __builtin_amdgcn_mfma_f32_16x16x32_bf16(a0, b0, acc, 0, 0, 0);

    s16x8 a1 = __builtin_bit_cast(s16x8, av1);
    s16x8 b1 = __builtin_bit_cast(s16x8, make_uint4(b10, b11, b12, b13));
    acc = __builtin_amdgcn_mfma_f32_16x16x32_bf16(a1, b1, acc, 0, 0, 0);
  }

  // acc layout (m89-verified): col = l&15, row(batch) = (l>>4)*4 + i
#pragma unroll
  for (int i = 0; i < 4; ++i)
    red[w][(q * 4 + i) * 16 + r] = acc[i];
  __syncthreads();

  // thread t handles output element row = t>>4 (batch), col = t&15 (channel)
  const float sum = red[0][tid] + red[1][tid] + red[2][tid] + red[3][tid];
  const int col = tid & 15;
  const int row = tid >> 4;
  out[(size_t)row * N + n0 + col] = sum * scaler[n0 + col];
}

extern "C" void kernel_launch(void* const* d_in, const int* in_sizes, int n_in,
                              void* d_out, int out_size, void* d_ws, size_t ws_size,
                              hipStream_t stream) {
  const float* act    = (const float*)d_in[0];
  const int*   wt     = (const int*)d_in[1];
  const float* scaler = (const float*)d_in[2];
  float*       out    = (float*)d_out;
  uint4*       afrag  = (uint4*)d_ws;   // 256 KB of A-fragments

  prep_a_kernel<<<(NSTEPS * 64) / 256, 256, 0, stream>>>(act, afrag);
  wq_linear_kernel<<<N / 16, 256, 0, stream>>>(wt, afrag, scaler, out);
}

// Round 4
// 220.506 us; speedup vs baseline: 1.2410x; 1.2410x over previous
//
#include <hip/hip_runtime.h>
#include <hip/hip_bf16.h>
#include <stdint.h>

// WeightOnlyPerChannelQuantizedLinear: out[b,n] = (sum_k x[b,k]*w[n,k]) * scale[n]
// x: fp32 [16][8192], w: int8 values stored as int32 [28672][8192], scale: fp32 [28672]
// HBM-bound on the 940 MB int32 weight stream. bf16 MFMA 16x16x32 (int8->bf16 exact).
//
// R4 vs R1 (211.6us) / R3 (273.7us, nt regression):
//  R1 post-mortem: 940MB weights + 448MB afrag re-reads = 1388MB @ 6.56TB/s = 212us.
//  The afrag table (256KB) is evicted from L2 every ~5us by the weight stream, so
//  per-k-step fragment re-reads mostly miss. Fix is structural, not a cache hint:
//  each wave loads its 8 A-fragments ONCE into VGPRs and reuses them across 8
//  n-tiles (128 channels/block). K split 8x across blocks (grid 224x8=1792),
//  4 waves split K within block, LDS reduce, f32 HW-atomic add into zeroed out.
//  A-traffic: 448MB -> ~56MB. Weight pattern identical to R1 (dense, no nt).

using f32x4 = __attribute__((ext_vector_type(4))) float;
using s16x8 = __attribute__((ext_vector_type(8))) short;
using i32x4 = __attribute__((ext_vector_type(4))) int;

static constexpr int K      = 8192;
static constexpr int N      = 28672;
static constexpr int NSTEPS = K / 32;       // 256 MFMA k-steps total
static constexpr int NT     = 128;          // channels per block
static constexpr int TILES  = NT / 16;      // 8 n-tiles
static constexpr int KS     = 8;            // k-split across blocks
static constexpr int KB     = K / KS;       // 1024 k per block
static constexpr int WAVES  = 4;
static constexpr int KWV    = KB / WAVES;   // 256 k per wave
static constexpr int SW     = KWV / 32;     // 8 MFMA steps per wave

// ---------------------------------------------------------------------------
// Pre-pass (R1 mapping): fp32 activations [16][K] -> bf16 MFMA A-fragments.
// Lane l=(q<<4)|row of step kk holds A[row][kk*32 + q*8 + j], j=0..7, packed as
// 4 dwords (even j low half), stored at afrag[kk*64 + l].
// ---------------------------------------------------------------------------
__global__ __launch_bounds__(256) void prep_a_kernel(const float* __restrict__ act,
                                                     uint4* __restrict__ afrag) {
  const int t   = blockIdx.x * 256 + threadIdx.x;  // 0 .. NSTEPS*64-1
  const int kk  = t >> 6;
  const int l   = t & 63;
  const int row = l & 15;
  const int q   = l >> 4;
  const float* src = act + row * K + kk * 32 + q * 8;
  uint d[4];
#pragma unroll
  for (int p = 0; p < 4; ++p) {
    uint u0 = __builtin_bit_cast(uint, src[2 * p]);
    uint u1 = __builtin_bit_cast(uint, src[2 * p + 1]);
    u0 += 0x7fffu + ((u0 >> 16) & 1u);            // RNE f32 -> bf16
    u1 += 0x7fffu + ((u1 >> 16) & 1u);
    d[p] = (u0 >> 16) | (u1 & 0xffff0000u);       // even j low, odd j high
  }
  afrag[t] = make_uint4(d[0], d[1], d[2], d[3]);
}

// pack two int weights' bf16 values (exact for |w|<=127)
__device__ __forceinline__ uint pack_bf16(int a, int b) {
  uint fa = __builtin_bit_cast(uint, (float)a);
  uint fb = __builtin_bit_cast(uint, (float)b);
  return (fa >> 16) | (fb & 0xffff0000u);
}

// ---------------------------------------------------------------------------
// Main kernel. Block (bn,bk): channels [bn*128, +128), k [bk*1024, +1024).
// Wave w owns k-sub [bk*1024 + w*256, +256) = 8 MFMA steps; loads its 8
// A-fragments once (32 VGPR), then loops 8 n-tiles reusing them.
// Per tile per step: 2x dwordx4 weight load (R1's dense pattern), pack, MFMA.
// Epilogue: LDS reduce over 4 waves, scale, one f32 atomic add per element.
// ---------------------------------------------------------------------------
__global__ __launch_bounds__(256) void wq_linear_kernel(
    const int* __restrict__ wt,        // int32 [N][K]
    const uint4* __restrict__ afrag,   // [NSTEPS][64]
    const float* __restrict__ scaler,  // [N]
    float* __restrict__ out) {         // [16][N], pre-zeroed
  __shared__ float red[WAVES * TILES * 256];
  const int tid = threadIdx.x;
  const int l   = tid & 63;
  const int w   = tid >> 6;
  const int n0  = blockIdx.x * NT;
  const int bk  = blockIdx.y;
  const int r   = l & 15;           // channel within 16-wide tile (B column)
  const int q   = l >> 4;           // k-chunk selector

  const int k0    = bk * KB + w * KWV;   // wave's k base
  const int step0 = bk * (KB / 32) + w * SW;

  // A-fragments: loaded once, reused across all 8 n-tiles.
  uint4 a[SW];
  {
    const uint4* ap = afrag + (size_t)step0 * 64 + l;
#pragma unroll
    for (int s = 0; s < SW; ++s) a[s] = ap[s * 64];
  }

#pragma unroll 1
  for (int t = 0; t < TILES; ++t) {
    const int* wrow = wt + (size_t)(n0 + t * 16 + r) * K + k0 + q * 8;
    f32x4 acc = {0.f, 0.f, 0.f, 0.f};
#pragma unroll
    for (int s = 0; s < SW; ++s) {
      const i32x4 w0 = *(const i32x4*)(wrow + s * 32);      // words q*8+0..3
      const i32x4 w1 = *(const i32x4*)(wrow + s * 32 + 4);  // words q*8+4..7
      const uint b0 = pack_bf16(w0.x, w0.y);
      const uint b1 = pack_bf16(w0.z, w0.w);
      const uint b2 = pack_bf16(w1.x, w1.y);
      const uint b3 = pack_bf16(w1.z, w1.w);
      s16x8 av = __builtin_bit_cast(s16x8, a[s]);
      s16x8 bv = __builtin_bit_cast(s16x8, make_uint4(b0, b1, b2, b3));
      acc = __builtin_amdgcn_mfma_f32_16x16x32_bf16(av, bv, acc, 0, 0, 0);
    }
    // acc layout (m89-verified): col = r, row(batch) = q*4 + i
#pragma unroll
    for (int i = 0; i < 4; ++i)
      red[(w * TILES + t) * 256 + (q * 4 + i) * 16 + r] = acc[i];
  }
  __syncthreads();

  // Reduce 4 waves' partials; one atomic per element per k-block.
  const int b = tid >> 4;        // batch row
  const int c = tid & 15;        // channel within tile
#pragma unroll
  for (int t = 0; t < TILES; ++t) {
    const float sum = red[(0 * TILES + t) * 256 + tid] +
                      red[(1 * TILES + t) * 256 + tid] +
                      red[(2 * TILES + t) * 256 + tid] +
                      red[(3 * TILES + t) * 256 + tid];
    const int ch = n0 + t * 16 + c;
    unsafeAtomicAdd(&out[(size_t)b * N + ch], sum * scaler[ch]);
  }
}

extern "C" void kernel_launch(void* const* d_in, const int* in_sizes, int n_in,
                              void* d_out, int out_size, void* d_ws, size_t ws_size,
                              hipStream_t stream) {
  const float* act    = (const float*)d_in[0];
  const int*   wt     = (const int*)d_in[1];
  const float* scaler = (const float*)d_in[2];
  float*       out    = (float*)d_out;
  uint4*       afrag  = (uint4*)d_ws;   // 256 KB of A-fragments

  hipMemsetAsync(out, 0, (size_t)out_size * sizeof(float), stream);
  prep_a_kernel<<<(NSTEPS * 64) / 256, 256, 0, stream>>>(act, afrag);
  dim3 grid(N / NT, KS);
  wq_linear_kernel<<<grid, 256, 0, stream>>>(wt, afrag, scaler, out);
}

// Round 5
// 191.151 us; speedup vs baseline: 1.4316x; 1.1536x over previous
//
#include <hip/hip_runtime.h>
#include <hip/hip_bf16.h>
#include <stdint.h>

// WeightOnlyPerChannelQuantizedLinear: out[b,n] = (sum_k x[b,k]*w[n,k]) * scale[n]
// x: fp32 [16][8192], w: int8 values stored as int32 [28672][8192], scale: fp32 [28672]
//
// R5 theory: R1/R4 both stream weights at ~4.4 TB/s because each wave interleaves
// 16 row-streams at 32KB stride, 128B per visit -> DRAM page thrash (~80K streams
// chip-wide vs ~1K open pages; 128B per activation caps at ~3-4.5 TB/s).
// Fix: 4 streams/wave, 2KB contiguous per row per window, staged through
// XOR-swizzled LDS (bf16), window split-k across waves, dbuf, 1 barrier/window.

using f32x4 = __attribute__((ext_vector_type(4))) float;
using s16x8 = __attribute__((ext_vector_type(8))) short;
using i32x4 = __attribute__((ext_vector_type(4))) int;

static constexpr int K      = 8192;
static constexpr int N      = 28672;
static constexpr int NSTEPS = K / 32;     // 256 MFMA k-steps total
static constexpr int WK     = 512;        // k per window
static constexpr int NWIN   = K / WK;     // 16 windows
static constexpr int WAVES  = 4;
static constexpr int SPW    = (WK / 32) / WAVES;  // 4 MFMA steps per wave per window
static constexpr int LPB    = 16384;      // LDS bytes per buffer: 16 rows * 512k * 2B

// ---------------------------------------------------------------------------
// Pre-pass (R1 mapping): lane l=(q<<4)|row of step kk holds A[row][kk*32+q*8+j],
// j=0..7, packed 4 dwords (even j low half), at afrag[kk*64 + l].
// ---------------------------------------------------------------------------
__global__ __launch_bounds__(256) void prep_a_kernel(const float* __restrict__ act,
                                                     uint4* __restrict__ afrag) {
  const int t   = blockIdx.x * 256 + threadIdx.x;
  const int kk  = t >> 6;
  const int l   = t & 63;
  const int row = l & 15;
  const int q   = l >> 4;
  const float* src = act + row * K + kk * 32 + q * 8;
  uint d[4];
#pragma unroll
  for (int p = 0; p < 4; ++p) {
    uint u0 = __builtin_bit_cast(uint, src[2 * p]);
    uint u1 = __builtin_bit_cast(uint, src[2 * p + 1]);
    u0 += 0x7fffu + ((u0 >> 16) & 1u);            // RNE f32 -> bf16
    u1 += 0x7fffu + ((u1 >> 16) & 1u);
    d[p] = (u0 >> 16) | (u1 & 0xffff0000u);
  }
  afrag[t] = make_uint4(d[0], d[1], d[2], d[3]);
}

__device__ __forceinline__ uint pack_bf16(int a, int b) {
  uint fa = __builtin_bit_cast(uint, (float)a);
  uint fb = __builtin_bit_cast(uint, (float)b);
  return (fa >> 16) | (fb & 0xffff0000u);   // exact for |w|<=127
}

// ---------------------------------------------------------------------------
// Main kernel. Block = 16 channels x full K. Per 512-k window:
//  load : wave w reads rows [w*4, w*4+4), 2KB contiguous each (lane c of a row
//         reads 16B chunks at c*64B + i*256B, i=0..7 -> dense 256B/instr bursts)
//  write: convert int32->bf16, ds_write_b64 at byte (row*1024 + k*2) ^ ((row&7)<<4)
//  mfma : window's 16 steps split 4/wave; B-frag = swizzled ds_read_b128,
//         A-frag = global afrag load (L2-resident, R1-proven). acc per wave.
// Double-buffered LDS (2 x 16KB), loads for m+1 issued before computing m,
// one __syncthreads per window. Epilogue: LDS reduce over waves, scale, store.
// ---------------------------------------------------------------------------
__global__ __launch_bounds__(256) void wq_linear_kernel(
    const int* __restrict__ wt,        // int32 [N][K]
    const uint4* __restrict__ afrag,   // [NSTEPS][64]
    const float* __restrict__ scaler,  // [N]
    float* __restrict__ out) {         // [16][N]
  __shared__ unsigned char lds[2][LPB];   // 32KB total; buf0 reused for reduce
  const int tid = threadIdx.x;
  const int l   = tid & 63;
  const int w   = tid >> 6;
  const int n0  = blockIdx.x << 4;
  const int r   = l & 15;           // compute: channel within tile (B column)
  const int q   = l >> 4;           // compute: k-chunk selector

  // loader role: 4 rows per wave, 16 lanes per row
  const int lrow = (w << 2) + (l >> 4);   // 0..15
  const int lc   = l & 15;                // 16B chunk within 256B segment
  const int* grow = wt + (size_t)(n0 + lrow) * K + lc * 4;
  const int wbase = ((lrow << 10) + (lc << 3)) ^ ((lrow & 7) << 4);

  f32x4 acc = {0.f, 0.f, 0.f, 0.f};
  i32x4 st[8];

  // prologue: window 0 loads
#pragma unroll
  for (int i = 0; i < 8; ++i) st[i] = *(const i32x4*)(grow + i * 64);
#pragma unroll
  for (int i = 0; i < 8; ++i) {
    uint2 v = {pack_bf16(st[i].x, st[i].y), pack_bf16(st[i].z, st[i].w)};
    *(uint2*)(&lds[0][wbase + i * 128]) = v;
  }
  __syncthreads();

#pragma unroll 1
  for (int m = 0; m < NWIN; ++m) {
    // issue next window's global loads first (overlap with compute below)
    if (m + 1 < NWIN) {
      const int* g = grow + (m + 1) * WK;
#pragma unroll
      for (int i = 0; i < 8; ++i) st[i] = *(const i32x4*)(g + i * 64);
    }

    // compute window m from lds[m&1]: steps w*4 .. w*4+3
    const unsigned char* buf = lds[m & 1];
#pragma unroll
    for (int s = 0; s < SPW; ++s) {
      const int stp = (w << 2) + s;                 // 0..15 within window
      const int kk  = m * (WK / 32) + stp;          // global MFMA step
      const uint4 av = afrag[(size_t)kk * 64 + l];
      const int rb = ((r << 10) + (stp << 6) + (q << 4)) ^ ((r & 7) << 4);
      const uint4 bv = *(const uint4*)(&buf[rb]);
      s16x8 a = __builtin_bit_cast(s16x8, av);
      s16x8 b = __builtin_bit_cast(s16x8, bv);
      acc = __builtin_amdgcn_mfma_f32_16x16x32_bf16(a, b, acc, 0, 0, 0);
    }

    // stage window m+1 into the other buffer
    if (m + 1 < NWIN) {
      unsigned char* dst = lds[(m + 1) & 1];
#pragma unroll
      for (int i = 0; i < 8; ++i) {
        uint2 v = {pack_bf16(st[i].x, st[i].y), pack_bf16(st[i].z, st[i].w)};
        *(uint2*)(&dst[wbase + i * 128]) = v;
      }
    }
    __syncthreads();
  }

  // epilogue: reduce 4 waves' split-k partials (reuse buf0 region as f32 scratch)
  float* red = (float*)&lds[0][0];
  // acc layout (m89-verified): col = r, row(batch) = q*4 + i
#pragma unroll
  for (int i = 0; i < 4; ++i)
    red[w * 256 + ((q << 2) + i) * 16 + r] = acc[i];
  __syncthreads();

  const float sum = red[0 * 256 + tid] + red[1 * 256 + tid] +
                    red[2 * 256 + tid] + red[3 * 256 + tid];
  const int col = tid & 15;
  const int row = tid >> 4;
  out[(size_t)row * N + n0 + col] = sum * scaler[n0 + col];
}

extern "C" void kernel_launch(void* const* d_in, const int* in_sizes, int n_in,
                              void* d_out, int out_size, void* d_ws, size_t ws_size,
                              hipStream_t stream) {
  const float* act    = (const float*)d_in[0];
  const int*   wt     = (const int*)d_in[1];
  const float* scaler = (const float*)d_in[2];
  float*       out    = (float*)d_out;
  uint4*       afrag  = (uint4*)d_ws;   // 256 KB of A-fragments

  prep_a_kernel<<<(NSTEPS * 64) / 256, 256, 0, stream>>>(act, afrag);
  wq_linear_kernel<<<N / 16, 256, 0, stream>>>(wt, afrag, scaler, out);
}